// Round 12
// baseline (150.440 us; speedup 1.0000x reference)
//
#include <hip/hip_runtime.h>

#define N_ELEM 4194304
constexpr int THREADS = 256;
constexpr int NQUAD   = N_ELEM / 4;          // 1048576 quads (4 rows each)
constexpr int BLOCKS  = NQUAD / THREADS;     // 4096 blocks = 2 residencies

// Fast single-instruction approximations. absmax headroom is enormous
// (R1/R11 measured 0.0 vs threshold 4.06e-2).
__device__ __forceinline__ float fast_rcp(float x)  { return __builtin_amdgcn_rcpf(x); }
__device__ __forceinline__ float fast_sqrt(float x) { return __builtin_amdgcn_sqrtf(x); }
__device__ __forceinline__ float fast_rsq(float x)  { return __builtin_amdgcn_rsqf(x); }

// Closed-form 2x2 symmetric spectral apply: f(A) = coef*(A - l1*I) + f(l1)*I,
// coef = (f(l2)-f(l1))/(l2-l1). Mirrors the jnp reference in fp32.
__device__ __forceinline__ float elem_loss(float pa, float pb, float pc,
                                           float ma, float mb, float mc) {
    // ---- E = exp(pred) ----
    float mid  = 0.5f * (pa + pc);
    float hd   = 0.5f * (pa - pc);
    float disc = fast_sqrt(fmaf(hd, hd, pb * pb));
    float l1 = mid - disc, l2 = mid + disc;
    float f1 = __expf(l1), f2 = __expf(l2);
    float coef = (f2 - f1) * fast_rcp(fmaxf(l2 - l1, 1e-12f));
    float ea = fmaf(coef, pa - l1, f1);
    float eb = coef * pb;
    float ec = fmaf(coef, pc - l1, f1);

    // ---- T = E^{-1/2} ----
    mid  = 0.5f * (ea + ec);
    hd   = 0.5f * (ea - ec);
    disc = fast_sqrt(fmaf(hd, hd, eb * eb));
    l1 = mid - disc; l2 = mid + disc;
    f1 = fast_rsq(l1); f2 = fast_rsq(l2);
    coef = (f2 - f1) * fast_rcp(fmaxf(l2 - l1, 1e-12f));
    float ta = fmaf(coef, ea - l1, f1);
    float tb = coef * eb;
    float tc = fmaf(coef, ec - l1, f1);

    // ---- P = T * M * T ----
    float u00 = fmaf(ma, ta, mb * tb);
    float u01 = fmaf(ma, tb, mb * tc);
    float u10 = fmaf(mb, ta, mc * tb);
    float u11 = fmaf(mb, tb, mc * tc);
    float p00 = fmaf(ta, u00, tb * u10);
    float p01 = fmaf(ta, u01, tb * u11);
    float p11 = fmaf(tb, u01, tc * u11);

    // ---- S = log(P) ----
    mid  = 0.5f * (p00 + p11);
    hd   = 0.5f * (p00 - p11);
    disc = fast_sqrt(fmaf(hd, hd, p01 * p01));
    l1 = mid - disc; l2 = mid + disc;
    f1 = __logf(l1); f2 = __logf(l2);
    coef = (f2 - f1) * fast_rcp(fmaxf(l2 - l1, 1e-12f));
    float sa = fmaf(coef, p00 - l1, f1);
    float sb = coef * p01;
    float sc = fmaf(coef, p11 - l1, f1);

    return fmaf(sa, sa, fmaf(2.0f * sb, sb, sc * sc));
}

__global__ __launch_bounds__(THREADS) void metric_loss_kernel(
        const float* __restrict__ pred,
        const float* __restrict__ act,
        float* __restrict__ out) {
    const float4* p4 = reinterpret_cast<const float4*>(pred);
    const float4* a4 = reinterpret_cast<const float4*>(act);

    // One quad (4 rows = 3 float4s per input) per thread; 4096 blocks give
    // 2 sequential residencies so replacement waves keep CUs + memory queue
    // fed through the drain (R1: one-shot residency left 60% idle time).
    const int q = blockIdx.x * THREADS + threadIdx.x;   // 0..NQUAD-1

    float4 P0 = p4[3 * q + 0];
    float4 P1 = p4[3 * q + 1];
    float4 P2 = p4[3 * q + 2];
    float4 A0 = a4[3 * q + 0];
    float4 A1 = a4[3 * q + 1];
    float4 A2 = a4[3 * q + 2];

    float acc = elem_loss(P0.x, P0.y, P0.z, A0.x, A0.y, A0.z)
              + elem_loss(P0.w, P1.x, P1.y, A0.w, A1.x, A1.y)
              + elem_loss(P1.z, P1.w, P2.x, A1.z, A1.w, A2.x)
              + elem_loss(P2.y, P2.z, P2.w, A2.y, A2.z, A2.w);

    // wave-64 reduce
    #pragma unroll
    for (int off = 32; off; off >>= 1)
        acc += __shfl_down(acc, off, 64);

    __shared__ float s[THREADS / 64];
    const int lane = threadIdx.x & 63;
    const int wid  = threadIdx.x >> 6;
    if (lane == 0) s[wid] = acc;
    __syncthreads();
    if (threadIdx.x == 0) {
        float bsum = s[0] + s[1] + s[2] + s[3];
        atomicAdd(out, bsum * (1.0f / (float)N_ELEM));
    }
}

extern "C" void kernel_launch(void* const* d_in, const int* in_sizes, int n_in,
                              void* d_out, int out_size, void* d_ws, size_t ws_size,
                              hipStream_t stream) {
    const float* pred = (const float*)d_in[0];
    const float* act  = (const float*)d_in[1];
    float* out = (float*)d_out;

    // d_out is poisoned to 0xAA before every timed launch; zero it first.
    hipMemsetAsync(out, 0, sizeof(float), stream);
    metric_loss_kernel<<<BLOCKS, THREADS, 0, stream>>>(pred, act, out);
}

// Round 13
// 125.147 us; speedup vs baseline: 1.2021x; 1.2021x over previous
//
#include <hip/hip_runtime.h>

#define N_ELEM 4194304
constexpr int THREADS = 256;
constexpr int BLOCKS  = 1024;
constexpr int ITERS   = 4;                    // quads per thread
constexpr int STRIDE  = BLOCKS * THREADS;     // 262144 quads per generation
// BLOCKS*THREADS*ITERS*4 == N_ELEM exactly.

__device__ __forceinline__ float fast_rcp(float x)  { return __builtin_amdgcn_rcpf(x); }
__device__ __forceinline__ float fast_sqrt(float x) { return __builtin_amdgcn_sqrtf(x); }
__device__ __forceinline__ float fast_rsq(float x)  { return __builtin_amdgcn_rsqf(x); }

// Closed-form 2x2 symmetric spectral apply: f(A) = coef*(A - l1*I) + f(l1)*I,
// coef = (f(l2)-f(l1))/(l2-l1). Mirrors the jnp reference in fp32.
__device__ __forceinline__ float elem_loss(float pa, float pb, float pc,
                                           float ma, float mb, float mc) {
    // ---- E = exp(pred) ----
    float mid  = 0.5f * (pa + pc);
    float hd   = 0.5f * (pa - pc);
    float disc = fast_sqrt(fmaf(hd, hd, pb * pb));
    float l1 = mid - disc, l2 = mid + disc;
    float f1 = __expf(l1), f2 = __expf(l2);
    float coef = (f2 - f1) * fast_rcp(fmaxf(l2 - l1, 1e-12f));
    float ea = fmaf(coef, pa - l1, f1);
    float eb = coef * pb;
    float ec = fmaf(coef, pc - l1, f1);

    // ---- T = E^{-1/2} ----
    mid  = 0.5f * (ea + ec);
    hd   = 0.5f * (ea - ec);
    disc = fast_sqrt(fmaf(hd, hd, eb * eb));
    l1 = mid - disc; l2 = mid + disc;
    f1 = fast_rsq(l1); f2 = fast_rsq(l2);
    coef = (f2 - f1) * fast_rcp(fmaxf(l2 - l1, 1e-12f));
    float ta = fmaf(coef, ea - l1, f1);
    float tb = coef * eb;
    float tc = fmaf(coef, ec - l1, f1);

    // ---- P = T * M * T ----
    float u00 = fmaf(ma, ta, mb * tb);
    float u01 = fmaf(ma, tb, mb * tc);
    float u10 = fmaf(mb, ta, mc * tb);
    float u11 = fmaf(mb, tb, mc * tc);
    float p00 = fmaf(ta, u00, tb * u10);
    float p01 = fmaf(ta, u01, tb * u11);
    float p11 = fmaf(tb, u01, tc * u11);

    // ---- S = log(P) ----
    mid  = 0.5f * (p00 + p11);
    hd   = 0.5f * (p00 - p11);
    disc = fast_sqrt(fmaf(hd, hd, p01 * p01));
    l1 = mid - disc; l2 = mid + disc;
    f1 = __logf(l1); f2 = __logf(l2);
    coef = (f2 - f1) * fast_rcp(fmaxf(l2 - l1, 1e-12f));
    float sa = fmaf(coef, p00 - l1, f1);
    float sb = coef * p01;
    float sc = fmaf(coef, p11 - l1, f1);

    return fmaf(sa, sa, fmaf(2.0f * sb, sb, sc * sc));
}

__device__ __forceinline__ float quad_loss(float4 p0, float4 p1, float4 p2,
                                           float4 a0, float4 a1, float4 a2) {
    float s = 0.0f;
    s += elem_loss(p0.x, p0.y, p0.z, a0.x, a0.y, a0.z);
    s += elem_loss(p0.w, p1.x, p1.y, a0.w, a1.x, a1.y);
    s += elem_loss(p1.z, p1.w, p2.x, a1.z, a1.w, a2.x);
    s += elem_loss(p2.y, p2.z, p2.w, a2.y, a2.z, a2.w);
    return s;
}

__global__ __launch_bounds__(THREADS) void metric_loss_kernel(
        const float* __restrict__ pred,
        const float* __restrict__ act,
        float* __restrict__ out) {
    const float4* p4 = reinterpret_cast<const float4*>(pred);
    const float4* a4 = reinterpret_cast<const float4*>(act);

    const int tid = blockIdx.x * THREADS + threadIdx.x;

    // Software pipeline: registers hold quad k while quad k+1's 6 loads are
    // in flight — memory service overlaps compute for ITERS-1 of ITERS
    // iterations (R11/R12 showed the load-all-then-compute structure
    // serializes the two phases: ~16-20us mem + ~12-18us compute = 40us).
    int base = 3 * tid;
    float4 P0 = p4[base + 0];
    float4 P1 = p4[base + 1];
    float4 P2 = p4[base + 2];
    float4 A0 = a4[base + 0];
    float4 A1 = a4[base + 1];
    float4 A2 = a4[base + 2];

    float acc = 0.0f;
    #pragma unroll
    for (int k = 1; k < ITERS; ++k) {
        const int nb = 3 * (tid + k * STRIDE);
        float4 nP0 = p4[nb + 0];
        float4 nP1 = p4[nb + 1];
        float4 nP2 = p4[nb + 2];
        float4 nA0 = a4[nb + 0];
        float4 nA1 = a4[nb + 1];
        float4 nA2 = a4[nb + 2];

        acc += quad_loss(P0, P1, P2, A0, A1, A2);

        P0 = nP0; P1 = nP1; P2 = nP2;
        A0 = nA0; A1 = nA1; A2 = nA2;
    }
    acc += quad_loss(P0, P1, P2, A0, A1, A2);

    // wave-64 reduce
    #pragma unroll
    for (int off = 32; off; off >>= 1)
        acc += __shfl_down(acc, off, 64);

    __shared__ float s[THREADS / 64];
    const int lane = threadIdx.x & 63;
    const int wid  = threadIdx.x >> 6;
    if (lane == 0) s[wid] = acc;
    __syncthreads();
    if (threadIdx.x == 0) {
        float bsum = s[0] + s[1] + s[2] + s[3];
        atomicAdd(out, bsum * (1.0f / (float)N_ELEM));
    }
}

extern "C" void kernel_launch(void* const* d_in, const int* in_sizes, int n_in,
                              void* d_out, int out_size, void* d_ws, size_t ws_size,
                              hipStream_t stream) {
    const float* pred = (const float*)d_in[0];
    const float* act  = (const float*)d_in[1];
    float* out = (float*)d_out;

    // d_out is poisoned to 0xAA before every timed launch; zero it first.
    hipMemsetAsync(out, 0, sizeof(float), stream);
    metric_loss_kernel<<<BLOCKS, THREADS, 0, stream>>>(pred, act, out);
}

// Round 19
// 116.499 us; speedup vs baseline: 1.2913x; 1.0742x over previous
//
#include <hip/hip_runtime.h>

#define N_ELEM 4194304
constexpr int THREADS       = 256;
constexpr int BLOCKS        = 1024;
constexpr int ITERS         = 4;
constexpr int ROWS_PER_TILE = 1024;                  // rows per block-iteration
constexpr int Q4_PER_TILE   = ROWS_PER_TILE * 3 / 4; // 768 float4s per input
// BLOCKS * ITERS * ROWS_PER_TILE == N_ELEM exactly.

__device__ __forceinline__ float fast_rcp(float x)  { return __builtin_amdgcn_rcpf(x); }
__device__ __forceinline__ float fast_sqrt(float x) { return __builtin_amdgcn_sqrtf(x); }
__device__ __forceinline__ float fast_rsq(float x)  { return __builtin_amdgcn_rsqf(x); }

// Closed-form 2x2 symmetric spectral apply: f(A) = coef*(A - l1*I) + f(l1)*I,
// coef = (f(l2)-f(l1))/(l2-l1). Mirrors the jnp reference in fp32.
__device__ __forceinline__ float elem_loss(float pa, float pb, float pc,
                                           float ma, float mb, float mc) {
    // ---- E = exp(pred) ----
    float mid  = 0.5f * (pa + pc);
    float hd   = 0.5f * (pa - pc);
    float disc = fast_sqrt(fmaf(hd, hd, pb * pb));
    float l1 = mid - disc, l2 = mid + disc;
    float f1 = __expf(l1), f2 = __expf(l2);
    float coef = (f2 - f1) * fast_rcp(fmaxf(l2 - l1, 1e-12f));
    float ea = fmaf(coef, pa - l1, f1);
    float eb = coef * pb;
    float ec = fmaf(coef, pc - l1, f1);

    // ---- T = E^{-1/2} ----
    mid  = 0.5f * (ea + ec);
    hd   = 0.5f * (ea - ec);
    disc = fast_sqrt(fmaf(hd, hd, eb * eb));
    l1 = mid - disc; l2 = mid + disc;
    f1 = fast_rsq(l1); f2 = fast_rsq(l2);
    coef = (f2 - f1) * fast_rcp(fmaxf(l2 - l1, 1e-12f));
    float ta = fmaf(coef, ea - l1, f1);
    float tb = coef * eb;
    float tc = fmaf(coef, ec - l1, f1);

    // ---- P = T * M * T ----
    float u00 = fmaf(ma, ta, mb * tb);
    float u01 = fmaf(ma, tb, mb * tc);
    float u10 = fmaf(mb, ta, mc * tb);
    float u11 = fmaf(mb, tb, mc * tc);
    float p00 = fmaf(ta, u00, tb * u10);
    float p01 = fmaf(ta, u01, tb * u11);
    float p11 = fmaf(tb, u01, tc * u11);

    // ---- S = log(P) ----
    mid  = 0.5f * (p00 + p11);
    hd   = 0.5f * (p00 - p11);
    disc = fast_sqrt(fmaf(hd, hd, p01 * p01));
    l1 = mid - disc; l2 = mid + disc;
    f1 = __logf(l1); f2 = __logf(l2);
    coef = (f2 - f1) * fast_rcp(fmaxf(l2 - l1, 1e-12f));
    float sa = fmaf(coef, p00 - l1, f1);
    float sb = coef * p01;
    float sc = fmaf(coef, p11 - l1, f1);

    return fmaf(sa, sa, fmaf(2.0f * sb, sb, sc * sc));
}

__global__ __launch_bounds__(THREADS) void metric_loss_kernel(
        const float* __restrict__ pred,
        const float* __restrict__ act,
        float* __restrict__ out) {
    const float4* p4 = reinterpret_cast<const float4*>(pred);
    const float4* a4 = reinterpret_cast<const float4*>(act);

    // SoA staging: soa[input][component][row]. 24 KB -> 6 blocks/CU; grid
    // puts 4 blocks/CU so all are resident. Global loads are perfectly
    // coalesced (lane-stride 16B); the stride-48B gather of R1-R13 (the
    // suspected ~1.5 TB/s read cap) is eliminated.
    __shared__ __attribute__((aligned(16))) float soa[2][3][ROWS_PER_TILE];

    const int t = threadIdx.x;

    float4 curP0, curP1, curP2, curA0, curA1, curA2;
    float4 nxtP0, nxtP1, nxtP2, nxtA0, nxtA1, nxtA2;

    {
        const int base = (blockIdx.x * ITERS) * Q4_PER_TILE;
        curP0 = p4[base + 0 * 256 + t];
        curP1 = p4[base + 1 * 256 + t];
        curP2 = p4[base + 2 * 256 + t];
        curA0 = a4[base + 0 * 256 + t];
        curA1 = a4[base + 1 * 256 + t];
        curA2 = a4[base + 2 * 256 + t];
    }

    float acc = 0.0f;

    #pragma unroll
    for (int it = 0; it < ITERS; ++it) {
        __syncthreads();   // previous iteration's LDS reads are complete

        // Scatter AoS registers -> SoA LDS. p = global float idx in tile,
        // r = p/3 (row), c = p%3 (component). Bijective: no write collisions.
        #pragma unroll
        for (int k = 0; k < 3; ++k) {
            const float4 vp = (k == 0) ? curP0 : (k == 1) ? curP1 : curP2;
            const float4 va = (k == 0) ? curA0 : (k == 1) ? curA1 : curA2;
            #pragma unroll
            for (int e = 0; e < 4; ++e) {
                const unsigned p = 1024u * k + 4u * t + e;
                const unsigned r = p / 3u;
                const unsigned c = p - 3u * r;
                const float fp = (e == 0) ? vp.x : (e == 1) ? vp.y : (e == 2) ? vp.z : vp.w;
                const float fa = (e == 0) ? va.x : (e == 1) ? va.y : (e == 2) ? va.z : va.w;
                soa[0][c][r] = fp;
                soa[1][c][r] = fa;
            }
        }

        // Prefetch next tile's globals into registers — in flight during
        // the barrier, LDS reads, and compute below.
        if (it + 1 < ITERS) {
            const int base = (blockIdx.x * ITERS + it + 1) * Q4_PER_TILE;
            nxtP0 = p4[base + 0 * 256 + t];
            nxtP1 = p4[base + 1 * 256 + t];
            nxtP2 = p4[base + 2 * 256 + t];
            nxtA0 = a4[base + 0 * 256 + t];
            nxtA1 = a4[base + 1 * 256 + t];
            nxtA2 = a4[base + 2 * 256 + t];
        }

        __syncthreads();   // SoA tile fully written

        // Conflict-free ds_read_b128: lane t reads rows 4t..4t+3 of each
        // component array (byte addr 16t — linear).
        const float4 Ap = *reinterpret_cast<const float4*>(&soa[0][0][4 * t]);
        const float4 Bp = *reinterpret_cast<const float4*>(&soa[0][1][4 * t]);
        const float4 Cp = *reinterpret_cast<const float4*>(&soa[0][2][4 * t]);
        const float4 Aa = *reinterpret_cast<const float4*>(&soa[1][0][4 * t]);
        const float4 Ba = *reinterpret_cast<const float4*>(&soa[1][1][4 * t]);
        const float4 Ca = *reinterpret_cast<const float4*>(&soa[1][2][4 * t]);

        acc += elem_loss(Ap.x, Bp.x, Cp.x, Aa.x, Ba.x, Ca.x);
        acc += elem_loss(Ap.y, Bp.y, Cp.y, Aa.y, Ba.y, Ca.y);
        acc += elem_loss(Ap.z, Bp.z, Cp.z, Aa.z, Ba.z, Ca.z);
        acc += elem_loss(Ap.w, Bp.w, Cp.w, Aa.w, Ba.w, Ca.w);

        curP0 = nxtP0; curP1 = nxtP1; curP2 = nxtP2;
        curA0 = nxtA0; curA1 = nxtA1; curA2 = nxtA2;
    }

    // wave-64 reduce
    #pragma unroll
    for (int off = 32; off; off >>= 1)
        acc += __shfl_down(acc, off, 64);

    __shared__ float s[THREADS / 64];
    const int lane = threadIdx.x & 63;
    const int wid  = threadIdx.x >> 6;
    if (lane == 0) s[wid] = acc;
    __syncthreads();
    if (threadIdx.x == 0) {
        float bsum = s[0] + s[1] + s[2] + s[3];
        atomicAdd(out, bsum * (1.0f / (float)N_ELEM));
    }
}

extern "C" void kernel_launch(void* const* d_in, const int* in_sizes, int n_in,
                              void* d_out, int out_size, void* d_ws, size_t ws_size,
                              hipStream_t stream) {
    const float* pred = (const float*)d_in[0];
    const float* act  = (const float*)d_in[1];
    float* out = (float*)d_out;

    // d_out is poisoned to 0xAA before every timed launch; zero it first.
    hipMemsetAsync(out, 0, sizeof(float), stream);
    metric_loss_kernel<<<BLOCKS, THREADS, 0, stream>>>(pred, act, out);
}